// Round 1
// baseline (167.362 us; speedup 1.0000x reference)
//
#include <hip/hip_runtime.h>
#include <hip/hip_bf16.h>
#include <cstdint>
#include <cmath>

// Problem constants — inputs/outputs are fp32 (verified R1 vs R2).
// LESSON (R5): cooperative grid.sync() costs ~50 us on MI355X — use kernel
// boundaries. LESSON (R6): scan topology is cheap; convert + GEMM staging and
// scatter patterns are the fat.
// R7 theory: [128][64] row-major LDS tiles = 16-way bank conflict on every
// fragment ds_read_b128 (bank = f(kk,quad) only, row-independent); plus the
// 2-barrier K-loop exposes full stage latency. Fix BOTH together (m252 regime
// lesson): BK=32 double-buffered single-barrier pipeline + (row>>1)&3 XOR slot
// swizzle (read side swizzled; lds-direct source pre-swizzled per rule #21).
#define T_SEQ 16384
#define DMODEL 512
#define NCHUNK 512        // scan chunks (= T_SEQ/LCHUNK)
#define LCHUNK 32
#define W_N    (DMODEL * DMODEL)
#define N4_W   (W_N / 4)
#define N4_W3  (3 * N4_W)
#define BK     32
#define NT     (DMODEL / BK)   // 16 K-steps

typedef __bf16 bf16x8 __attribute__((ext_vector_type(8)));
typedef float  f32x4  __attribute__((ext_vector_type(4)));

using bf16 = __hip_bfloat16;

__device__ __forceinline__ void load_lds16(const void* g, void* l) {
    __builtin_amdgcn_global_load_lds((const __attribute__((address_space(1))) void*)g,
                                     (__attribute__((address_space(3))) void*)l,
                                     16, 0, 0);
}

__device__ __forceinline__ unsigned short f2bf(float f) {
    union { float f; unsigned u; } v; v.f = f;
    const unsigned r = (v.u + 0x7FFFu + ((v.u >> 16) & 1u)) >> 16;
    return (unsigned short)r;
}
__device__ __forceinline__ float bf2f(unsigned short u) {
    union { unsigned u; float f; } v; v.u = ((unsigned)u) << 16;
    return v.f;
}

// ordered pair-combine: first=(fA,fB) then second=(sA,sB)
__device__ __forceinline__ void comb(float& A, float& B, float fA, float fB,
                                     float sA, float sB) {
    A = fA * sA;
    B = sA * fB + sB;
}

// ---------------------------------------------------------------------------
// Kernel 0: convert Wz, Wh, Wo fp32 -> bf16 (weights only; xs fused into
// gemm_zh staging). 3 MB total.
// ---------------------------------------------------------------------------
__global__ __launch_bounds__(256) void k_convert_w(
    const float* __restrict__ Wz, const float* __restrict__ Wh,
    const float* __restrict__ Wo,
    bf16* __restrict__ Wz_c, bf16* __restrict__ Wh_c, bf16* __restrict__ Wo_c)
{
    const int i = blockIdx.x * 256 + threadIdx.x;
    if (i >= N4_W3) return;
    const int w = i >> 16;
    const int o = i & 65535;
    const float* src = (w == 0) ? Wz : (w == 1) ? Wh : Wo;
    bf16* dst = (w == 0) ? Wz_c : (w == 1) ? Wh_c : Wo_c;
    const float4 v = ((const float4*)src)[o];
    ushort4 r;
    r.x = f2bf(v.x); r.y = f2bf(v.y); r.z = f2bf(v.z); r.w = f2bf(v.w);
    ((ushort4*)dst)[o] = r;
}

// ---------------------------------------------------------------------------
// Kernel 1: fused dual GEMM + scan phase 1.
// BK=32, double-buffered LDS, ONE barrier per K-step: stage(t+1) issued
// before compute(t) so HBM/L2 latency hides under MFMA+ds_read.
// LDS slot swizzle: physical 16B slot = logical_slot ^ ((row>>1)&3)
//  -> fragment reads are conflict-free (8 bank-clusters x 2 lanes).
// ---------------------------------------------------------------------------
__global__ __launch_bounds__(256, 2) void gemm_zh(
    const float* __restrict__ xs, const bf16* __restrict__ Wz, const float* __restrict__ bz,
    const bf16* __restrict__ Wh, const float* __restrict__ bh,
    unsigned int* __restrict__ ab_ws,
    float* __restrict__ AaggT, float* __restrict__ BaggT)
{
    __shared__ __bf16 As[2][128 * BK];
    __shared__ __bf16 Zs[2][128 * BK];
    __shared__ __bf16 Hs[2][128 * BK];

    const int tid  = threadIdx.x;
    const int bm   = blockIdx.x;   // 0..127 (M tile)
    const int bn   = blockIdx.y;   // 0..3   (N tile)
    const int lane = tid & 63;
    const int wave = tid >> 6;
    const int wm   = wave >> 1;
    const int wn   = wave & 1;
    const int quad = lane >> 4;
    const int col  = lane & 15;

    f32x4 accz[4][4], acch[4][4];
    #pragma unroll
    for (int i = 0; i < 4; ++i)
        #pragma unroll
        for (int j = 0; j < 4; ++j) {
            accz[i][j] = (f32x4){0.f, 0.f, 0.f, 0.f};
            acch[i][j] = (f32x4){0.f, 0.f, 0.f, 0.f};
        }

    // W staging (lds-direct, linear LDS dest; global source pre-swizzled):
    // physical slot (row, q=tid&3) holds global chunk q ^ ((row>>1)&3).
    const int wrow = tid >> 2;                       // +64 for it=1
    const int wq   = (tid & 3) ^ ((tid >> 3) & 3);   // constant per thread
    const bf16* zg = Wz + (size_t)(bn * 128 + wrow) * DMODEL + wq * 8;
    const bf16* hg = Wh + (size_t)(bn * 128 + wrow) * DMODEL + wq * 8;

    // xs staging (fp32 -> bf16 register path, swizzled ds_write)
    const int frow = tid >> 3;                       // +32 per it (4 its)
    const int f4   = tid & 7;                        // float4 within 32-col row
    const float* xg = xs + ((size_t)(bm * 128) + frow) * DMODEL + f4 * 4;
    const int xoff = frow * BK + ((((f4 >> 1) ^ ((frow >> 1) & 3))) << 3) + (f4 & 1) * 4;

    // fragment read offsets (swizzled; constant across K-steps)
    const int fq = quad ^ ((col >> 1) & 3);
    int offA[4], offB[4];
    #pragma unroll
    for (int i = 0; i < 4; ++i) {
        offA[i] = (wm * 64 + i * 16 + col) * BK + fq * 8;
        offB[i] = (wn * 64 + i * 16 + col) * BK + fq * 8;
    }

    float4 xr[4];

    auto XLOAD = [&](int t) {
        const int k0 = t * BK;
        #pragma unroll
        for (int it = 0; it < 4; ++it)
            xr[it] = *(const float4*)(xg + (size_t)(it * 32) * DMODEL + k0);
    };
    auto STAGE_W = [&](int t, int p) {
        const int k0 = t * BK;
        #pragma unroll
        for (int it = 0; it < 2; ++it) {
            const int chunk = it * 256 + tid;
            load_lds16(zg + (size_t)(it * 64) * DMODEL + k0, &Zs[p][chunk * 8]);
            load_lds16(hg + (size_t)(it * 64) * DMODEL + k0, &Hs[p][chunk * 8]);
        }
    };
    auto XWRITE = [&](int p) {
        #pragma unroll
        for (int it = 0; it < 4; ++it) {
            __hip_bfloat162 p0 = __float22bfloat162_rn(make_float2(xr[it].x, xr[it].y));
            __hip_bfloat162 p1 = __float22bfloat162_rn(make_float2(xr[it].z, xr[it].w));
            uint2 pk;
            pk.x = *(const unsigned*)&p0;
            pk.y = *(const unsigned*)&p1;
            *(uint2*)&As[p][xoff + it * 32 * BK] = pk;
        }
    };
    auto COMPUTE = [&](int p) {
        bf16x8 af[4], zf[4], hf[4];
        #pragma unroll
        for (int i = 0; i < 4; ++i) {
            af[i] = *(const bf16x8*)&As[p][offA[i]];
            zf[i] = *(const bf16x8*)&Zs[p][offB[i]];
            hf[i] = *(const bf16x8*)&Hs[p][offB[i]];
        }
        #pragma unroll
        for (int i = 0; i < 4; ++i)
            #pragma unroll
            for (int j = 0; j < 4; ++j) {
                accz[i][j] = __builtin_amdgcn_mfma_f32_16x16x32_bf16(af[i], zf[j], accz[i][j], 0, 0, 0);
                acch[i][j] = __builtin_amdgcn_mfma_f32_16x16x32_bf16(af[i], hf[j], acch[i][j], 0, 0, 0);
            }
    };

    // prologue: fill buffer 0
    XLOAD(0); STAGE_W(0, 0); XWRITE(0);
    __syncthreads();
    for (int t = 0; t < NT - 1; ++t) {
        const int p = t & 1;
        XLOAD(t + 1);            // issue xs loads first (vmcnt-friendly)
        STAGE_W(t + 1, p ^ 1);   // lds-direct into other buffer, in flight over compute
        COMPUTE(p);
        XWRITE(p ^ 1);           // xr arrived during compute
        __syncthreads();         // single drain+barrier per K-step
    }
    COMPUTE((NT - 1) & 1);

    // epilogue: D layout col=lane&15 (n), row=quad*4+reg (m)
    const int c_lo = bm * 4 + wm * 2;
    #pragma unroll
    for (int j = 0; j < 4; ++j) {
        const int n = bn * 128 + wn * 64 + j * 16 + col;
        const float bzv = bz[n];
        const float bhv = bh[n];
        float cA[4], cB[4];
        #pragma unroll
        for (int i = 0; i < 4; ++i) {
            const int mbase = bm * 128 + wm * 64 + i * 16 + quad * 4;
            float A = 1.f, B = 0.f;
            #pragma unroll
            for (int r = 0; r < 4; ++r) {
                const float zpre = accz[i][j][r] + bzv;
                const float hpre = acch[i][j][r] + bhv;
                const float z = 1.f / (1.f + __expf(-zpre));
                const float a = 1.f - z;
                const float b = z * hpre;
                const size_t idx = (size_t)(mbase + r) * DMODEL + n;
                ab_ws[idx] = (unsigned)f2bf(a) | ((unsigned)f2bf(b) << 16);
                A = a * A;
                B = a * B + b;
            }
            cA[i] = A; cB[i] = B;
        }
        #pragma unroll
        for (int i = 0; i < 4; ++i) {
            float pA = __shfl_xor(cA[i], 16);
            float pB = __shfl_xor(cB[i], 16);
            const bool hi1 = quad & 1;
            comb(cA[i], cB[i], hi1 ? pA : cA[i], hi1 ? pB : cB[i],
                               hi1 ? cA[i] : pA, hi1 ? cB[i] : pB);
            pA = __shfl_xor(cA[i], 32);
            pB = __shfl_xor(cB[i], 32);
            const bool hi2 = quad >> 1;
            comb(cA[i], cB[i], hi2 ? pA : cA[i], hi2 ? pB : cB[i],
                               hi2 ? cA[i] : pA, hi2 ? cB[i] : pB);
        }
        float Alo, Blo, Ahi, Bhi;
        comb(Alo, Blo, cA[0], cB[0], cA[1], cB[1]);
        comb(Ahi, Bhi, cA[2], cB[2], cA[3], cB[3]);
        if (quad == 0) {   // transposed [h][c] stores (scattered, overlapped)
            AaggT[(size_t)n * NCHUNK + c_lo]     = Alo;
            BaggT[(size_t)n * NCHUNK + c_lo]     = Blo;
            AaggT[(size_t)n * NCHUNK + c_lo + 1] = Ahi;
            BaggT[(size_t)n * NCHUNK + c_lo + 1] = Bhi;
        }
    }
}

// ---------------------------------------------------------------------------
// Kernel 2: per-channel Hillis-Steele over NCHUNK chunk aggregates.
// grid = 512 channel-blocks x 512 threads. Fully coalesced r/w via [h][c].
// ---------------------------------------------------------------------------
__global__ __launch_bounds__(512) void scan_p2(
    const float* __restrict__ AaggT, const float* __restrict__ BaggT,
    float* __restrict__ HpreT)
{
    const int h = blockIdx.x;
    const int c = threadIdx.x;
    __shared__ float sA[NCHUNK], sB[NCHUNK];

    float A = AaggT[(size_t)h * NCHUNK + c];
    float B = BaggT[(size_t)h * NCHUNK + c];
    sA[c] = A; sB[c] = B;
    __syncthreads();

    for (int off = 1; off < NCHUNK; off <<= 1) {
        float pA = 1.f, pB = 0.f;
        if (c >= off) { pA = sA[c - off]; pB = sB[c - off]; }
        __syncthreads();
        const float nB = A * pB + B;   // uses old A
        const float nA = A * pA;
        A = nA; B = nB;
        sA[c] = A; sB[c] = B;
        __syncthreads();
    }
    const float hp = (c == 0) ? 0.f : sB[c - 1];
    HpreT[(size_t)h * NCHUNK + c] = hp;
}

// ---------------------------------------------------------------------------
// Kernel 3: replay chunk recurrence from HpreT; write bf16 states.
// R7: 1 channel/thread, grid (512 chunks x 2 halves) x 256 threads
// -> 4 blocks/CU (2x TLP vs before) for this latency-sensitive 50 MB stream.
// ---------------------------------------------------------------------------
__global__ __launch_bounds__(256) void scan_p3(
    const unsigned int* __restrict__ ab_ws, const float* __restrict__ HpreT,
    unsigned short* __restrict__ states)
{
    const int tid = threadIdx.x;
    const int c   = blockIdx.x;
    const int ch  = blockIdx.y * 256 + tid;
    float H = HpreT[(size_t)ch * NCHUNK + c];       // one-time gather
    const size_t base = (size_t)(c * LCHUNK) * DMODEL + ch;
    #pragma unroll 8
    for (int i = 0; i < LCHUNK; ++i) {
        const unsigned u = ab_ws[base + (size_t)i * DMODEL];
        const float a = bf2f((unsigned short)(u & 0xFFFFu));
        const float b = bf2f((unsigned short)(u >> 16));
        H = a * H + b;
        states[base + (size_t)i * DMODEL] = f2bf(H);
    }
}

// ---------------------------------------------------------------------------
// Kernel 4: out = states @ Wo^T + bo  (fp32 out). grid dim3(128,4), bm fast.
// Same BK=32 single-barrier double-buffered pipeline + swizzle as gemm_zh.
// ---------------------------------------------------------------------------
__global__ __launch_bounds__(256, 2) void gemm_out(
    const bf16* __restrict__ states, const bf16* __restrict__ Wo, const float* __restrict__ bo,
    float* __restrict__ out)
{
    __shared__ __bf16 As[2][128 * BK];
    __shared__ __bf16 Bs[2][128 * BK];

    const int tid  = threadIdx.x;
    const int bm   = blockIdx.x;
    const int bn   = blockIdx.y;
    const int lane = tid & 63;
    const int wave = tid >> 6;
    const int wm   = wave >> 1;
    const int wn   = wave & 1;
    const int quad = lane >> 4;
    const int col  = lane & 15;

    f32x4 acc[4][4];
    #pragma unroll
    for (int i = 0; i < 4; ++i)
        #pragma unroll
        for (int j = 0; j < 4; ++j)
            acc[i][j] = (f32x4){0.f, 0.f, 0.f, 0.f};

    const int wrow = tid >> 2;
    const int wq   = (tid & 3) ^ ((tid >> 3) & 3);
    const bf16* ag = states + (size_t)(bm * 128 + wrow) * DMODEL + wq * 8;
    const bf16* bg = Wo     + (size_t)(bn * 128 + wrow) * DMODEL + wq * 8;

    const int fq = quad ^ ((col >> 1) & 3);
    int offA[4], offB[4];
    #pragma unroll
    for (int i = 0; i < 4; ++i) {
        offA[i] = (wm * 64 + i * 16 + col) * BK + fq * 8;
        offB[i] = (wn * 64 + i * 16 + col) * BK + fq * 8;
    }

    auto STAGE = [&](int t, int p) {
        const int k0 = t * BK;
        #pragma unroll
        for (int it = 0; it < 2; ++it) {
            const int chunk = it * 256 + tid;
            load_lds16(ag + (size_t)(it * 64) * DMODEL + k0, &As[p][chunk * 8]);
            load_lds16(bg + (size_t)(it * 64) * DMODEL + k0, &Bs[p][chunk * 8]);
        }
    };
    auto COMPUTE = [&](int p) {
        bf16x8 af[4], bf[4];
        #pragma unroll
        for (int i = 0; i < 4; ++i) {
            af[i] = *(const bf16x8*)&As[p][offA[i]];
            bf[i] = *(const bf16x8*)&Bs[p][offB[i]];
        }
        #pragma unroll
        for (int i = 0; i < 4; ++i)
            #pragma unroll
            for (int j = 0; j < 4; ++j)
                acc[i][j] = __builtin_amdgcn_mfma_f32_16x16x32_bf16(af[i], bf[j], acc[i][j], 0, 0, 0);
    };

    STAGE(0, 0);
    __syncthreads();
    for (int t = 0; t < NT - 1; ++t) {
        const int p = t & 1;
        STAGE(t + 1, p ^ 1);
        COMPUTE(p);
        __syncthreads();
    }
    COMPUTE((NT - 1) & 1);

    #pragma unroll
    for (int j = 0; j < 4; ++j) {
        const int n = bn * 128 + wn * 64 + j * 16 + col;
        const float bov = bo[n];
        #pragma unroll
        for (int i = 0; i < 4; ++i) {
            const int mbase = bm * 128 + wm * 64 + i * 16 + quad * 4;
            #pragma unroll
            for (int r = 0; r < 4; ++r)
                out[(size_t)(mbase + r) * DMODEL + n] = acc[i][j][r] + bov;
        }
    }
}

// ---------------------------------------------------------------------------
extern "C" void kernel_launch(void* const* d_in, const int* in_sizes, int n_in,
                              void* d_out, int out_size, void* d_ws, size_t ws_size,
                              hipStream_t stream)
{
    const float* xs = (const float*)d_in[0];
    const float* Wz = (const float*)d_in[1];
    const float* bz = (const float*)d_in[2];
    const float* Wh = (const float*)d_in[3];
    const float* bh = (const float*)d_in[4];
    const float* Wo = (const float*)d_in[5];
    const float* bo = (const float*)d_in[6];
    float* out = (float*)d_out;

    char* w = (char*)d_ws;
    bf16*  Wz_c   = (bf16*) (w);                     //    524,288
    bf16*  Wh_c   = (bf16*) (w + 524288ull);         //    524,288
    bf16*  Wo_c   = (bf16*) (w + 1048576ull);        //    524,288
    unsigned int*   ab_ws  = (unsigned int*)  (w + 1572864ull);  // 33,554,432
    unsigned short* states = (unsigned short*)(w + 35127296ull); // 16,777,216
    float* AaggT  = (float*)(w + 51904512ull);       //  1,048,576
    float* BaggT  = (float*)(w + 52953088ull);       //  1,048,576
    float* HpreT  = (float*)(w + 54001664ull);       //  1,048,576

    k_convert_w<<<(N4_W3 + 255) / 256, 256, 0, stream>>>(Wz, Wh, Wo, Wz_c, Wh_c, Wo_c);
    gemm_zh<<<dim3(128, 4), 256, 0, stream>>>(xs, Wz_c, bz, Wh_c, bh, ab_ws, AaggT, BaggT);
    scan_p2<<<DMODEL, NCHUNK, 0, stream>>>(AaggT, BaggT, HpreT);
    scan_p3<<<dim3(NCHUNK, 2), 256, 0, stream>>>(ab_ws, HpreT, states);
    gemm_out<<<dim3(128, 4), 256, 0, stream>>>((const bf16*)states, Wo_c, bo, out);
}

// Round 2
// 151.780 us; speedup vs baseline: 1.1027x; 1.1027x over previous
//
#include <hip/hip_runtime.h>
#include <hip/hip_bf16.h>
#include <cstdint>
#include <cmath>

// Problem constants — inputs/outputs are fp32.
// LESSON (R5): cooperative grid.sync() costs ~50 us on MI355X — use kernel
// boundaries. LESSON (R6): scan topology is cheap; convert + GEMM staging and
// scatter patterns are the fat.
// LESSON (R7): [128][64] row-major LDS = 16-way bank conflict; XOR slot
// swizzle fixes it (SQ_LDS_BANK_CONFLICT -> 0, verified).
// LESSON (R8 = this round's input): __syncthreads() drains vmcnt(0) every
// K-step — BK=32 halved compute per drain and REGRESSED (57us, MfmaUtil 10%,
// occupancy 14%: latency-bound). Fix = T4 counted vmcnt + raw s_barrier,
// depth-2 prefetch over 3 LDS buffers; all staging homogeneous
// global_load_lds (xs pre-converted to bf16 in k_convert, aliased onto the
// 'states' workspace region which is dead until scan_p3).
#define T_SEQ 16384
#define DMODEL 512
#define NCHUNK 512        // scan chunks (= T_SEQ/LCHUNK)
#define LCHUNK 32
#define W_N    (DMODEL * DMODEL)
#define N4_W   (W_N / 4)
#define N4_W3  (3 * N4_W)
#define N4_X   (T_SEQ * DMODEL / 4)
#define N4_ALL (N4_W3 + N4_X)
#define BK     32
#define NT     (DMODEL / BK)   // 16 K-steps

typedef __bf16 bf16x8 __attribute__((ext_vector_type(8)));
typedef float  f32x4  __attribute__((ext_vector_type(4)));

using bf16 = __hip_bfloat16;

__device__ __forceinline__ void load_lds16(const void* g, void* l) {
    __builtin_amdgcn_global_load_lds((const __attribute__((address_space(1))) void*)g,
                                     (__attribute__((address_space(3))) void*)l,
                                     16, 0, 0);
}

__device__ __forceinline__ unsigned short f2bf(float f) {
    union { float f; unsigned u; } v; v.f = f;
    const unsigned r = (v.u + 0x7FFFu + ((v.u >> 16) & 1u)) >> 16;
    return (unsigned short)r;
}
__device__ __forceinline__ float bf2f(unsigned short u) {
    union { unsigned u; float f; } v; v.u = ((unsigned)u) << 16;
    return v.f;
}

// ordered pair-combine: first=(fA,fB) then second=(sA,sB)
__device__ __forceinline__ void comb(float& A, float& B, float fA, float fB,
                                     float sA, float sB) {
    A = fA * sA;
    B = sA * fB + sB;
}

// ---------------------------------------------------------------------------
// Kernel 0: convert Wz, Wh, Wo AND xs fp32 -> bf16. ~52 MB traffic (~8 us).
// Paying this here buys gemm_zh a homogeneous global_load_lds staging path
// (counted-vmcnt pipeline) and halves its xs read volume.
// ---------------------------------------------------------------------------
__global__ __launch_bounds__(256) void k_convert(
    const float* __restrict__ xs,
    const float* __restrict__ Wz, const float* __restrict__ Wh,
    const float* __restrict__ Wo,
    bf16* __restrict__ xs_c, bf16* __restrict__ Wz_c,
    bf16* __restrict__ Wh_c, bf16* __restrict__ Wo_c)
{
    const int i = blockIdx.x * 256 + threadIdx.x;
    if (i >= N4_ALL) return;
    const float* src; bf16* dst; int o;
    if (i < N4_W3) {
        const int w = i >> 16; o = i & 65535;
        src = (w == 0) ? Wz : (w == 1) ? Wh : Wo;
        dst = (w == 0) ? Wz_c : (w == 1) ? Wh_c : Wo_c;
    } else {
        o = i - N4_W3; src = xs; dst = xs_c;
    }
    const float4 v = ((const float4*)src)[o];
    ushort4 r;
    r.x = f2bf(v.x); r.y = f2bf(v.y); r.z = f2bf(v.z); r.w = f2bf(v.w);
    ((ushort4*)dst)[o] = r;
}

// ---------------------------------------------------------------------------
// Kernel 1: fused dual GEMM + scan phase 1.
// Depth-2 counted-vmcnt pipeline (T3+T4): 3 LDS buffers, raw s_barrier,
// s_waitcnt vmcnt(6) in steady state (6 vm-ops/thread/stage in flight for
// the NEXT tile), vmcnt(0) only at the last K-step. LDS slot swizzle
// (physical 16B slot = logical ^ ((row>>1)&3)) keeps ds_read conflict-free;
// lds-direct source is pre-swizzled (both-sides rule).
// ---------------------------------------------------------------------------
__global__ __launch_bounds__(256, 2) void gemm_zh(
    const bf16* __restrict__ xs_c, const bf16* __restrict__ Wz, const float* __restrict__ bz,
    const bf16* __restrict__ Wh, const float* __restrict__ bh,
    unsigned int* __restrict__ ab_ws,
    float* __restrict__ AaggT, float* __restrict__ BaggT)
{
    __shared__ __bf16 As[3][128 * BK];
    __shared__ __bf16 Zs[3][128 * BK];
    __shared__ __bf16 Hs[3][128 * BK];

    const int tid  = threadIdx.x;
    const int bm   = blockIdx.x;   // 0..127 (M tile)
    const int bn   = blockIdx.y;   // 0..3   (N tile)
    const int lane = tid & 63;
    const int wave = tid >> 6;
    const int wm   = wave >> 1;
    const int wn   = wave & 1;
    const int quad = lane >> 4;
    const int col  = lane & 15;

    f32x4 accz[4][4], acch[4][4];
    #pragma unroll
    for (int i = 0; i < 4; ++i)
        #pragma unroll
        for (int j = 0; j < 4; ++j) {
            accz[i][j] = (f32x4){0.f, 0.f, 0.f, 0.f};
            acch[i][j] = (f32x4){0.f, 0.f, 0.f, 0.f};
        }

    // staging (lds-direct, linear LDS dest; global source pre-swizzled):
    // physical slot (row, q=tid&3) holds global chunk q ^ ((row>>1)&3).
    const int wrow = tid >> 2;                       // 0..63, +64 for it=1
    const int wq   = (tid & 3) ^ ((tid >> 3) & 3);   // constant per thread
    const bf16* ag = xs_c + (size_t)(bm * 128 + wrow) * DMODEL + wq * 8;
    const bf16* zg = Wz   + (size_t)(bn * 128 + wrow) * DMODEL + wq * 8;
    const bf16* hg = Wh   + (size_t)(bn * 128 + wrow) * DMODEL + wq * 8;

    // fragment read offsets (swizzled; constant across K-steps)
    const int fq = quad ^ ((col >> 1) & 3);
    int offA[4], offB[4];
    #pragma unroll
    for (int i = 0; i < 4; ++i) {
        offA[i] = (wm * 64 + i * 16 + col) * BK + fq * 8;
        offB[i] = (wn * 64 + i * 16 + col) * BK + fq * 8;
    }

    auto STAGE = [&](int t, int p) {
        const int k0 = t * BK;
        #pragma unroll
        for (int it = 0; it < 2; ++it) {
            const int chunk = it * 256 + tid;
            load_lds16(ag + (size_t)(it * 64) * DMODEL + k0, &As[p][chunk * 8]);
            load_lds16(zg + (size_t)(it * 64) * DMODEL + k0, &Zs[p][chunk * 8]);
            load_lds16(hg + (size_t)(it * 64) * DMODEL + k0, &Hs[p][chunk * 8]);
        }
    };
    auto COMPUTE = [&](int p) {
        bf16x8 af[4], zf[4], hf[4];
        #pragma unroll
        for (int i = 0; i < 4; ++i) {
            af[i] = *(const bf16x8*)&As[p][offA[i]];
            zf[i] = *(const bf16x8*)&Zs[p][offB[i]];
            hf[i] = *(const bf16x8*)&Hs[p][offB[i]];
        }
        #pragma unroll
        for (int i = 0; i < 4; ++i)
            #pragma unroll
            for (int j = 0; j < 4; ++j) {
                accz[i][j] = __builtin_amdgcn_mfma_f32_16x16x32_bf16(af[i], zf[j], accz[i][j], 0, 0, 0);
                acch[i][j] = __builtin_amdgcn_mfma_f32_16x16x32_bf16(af[i], hf[j], acch[i][j], 0, 0, 0);
            }
    };

    // prologue: two tiles in flight
    STAGE(0, 0); STAGE(1, 1);
    int pc = 0;   // buffer holding tile t
    for (int t = 0; t < NT - 1; ++t) {
        asm volatile("s_waitcnt vmcnt(6)" ::: "memory");   // tile t landed
        __builtin_amdgcn_s_barrier();                      // all waves' data in
        __builtin_amdgcn_sched_barrier(0);
        if (t + 2 < NT) {
            const int pn = (pc == 0) ? 2 : pc - 1;         // (pc+2)%3
            STAGE(t + 2, pn);                              // stays in flight
        }
        COMPUTE(pc);
        pc = (pc == 2) ? 0 : pc + 1;
    }
    asm volatile("s_waitcnt vmcnt(0)" ::: "memory");
    __builtin_amdgcn_s_barrier();
    __builtin_amdgcn_sched_barrier(0);
    COMPUTE(pc);

    // epilogue: D layout col=lane&15 (n), row=quad*4+reg (m)
    const int c_lo = bm * 4 + wm * 2;
    #pragma unroll
    for (int j = 0; j < 4; ++j) {
        const int n = bn * 128 + wn * 64 + j * 16 + col;
        const float bzv = bz[n];
        const float bhv = bh[n];
        float cA[4], cB[4];
        #pragma unroll
        for (int i = 0; i < 4; ++i) {
            const int mbase = bm * 128 + wm * 64 + i * 16 + quad * 4;
            float A = 1.f, B = 0.f;
            #pragma unroll
            for (int r = 0; r < 4; ++r) {
                const float zpre = accz[i][j][r] + bzv;
                const float hpre = acch[i][j][r] + bhv;
                const float z = 1.f / (1.f + __expf(-zpre));
                const float a = 1.f - z;
                const float b = z * hpre;
                const size_t idx = (size_t)(mbase + r) * DMODEL + n;
                ab_ws[idx] = (unsigned)f2bf(a) | ((unsigned)f2bf(b) << 16);
                A = a * A;
                B = a * B + b;
            }
            cA[i] = A; cB[i] = B;
        }
        #pragma unroll
        for (int i = 0; i < 4; ++i) {
            float pA = __shfl_xor(cA[i], 16);
            float pB = __shfl_xor(cB[i], 16);
            const bool hi1 = quad & 1;
            comb(cA[i], cB[i], hi1 ? pA : cA[i], hi1 ? pB : cB[i],
                               hi1 ? cA[i] : pA, hi1 ? cB[i] : pB);
            pA = __shfl_xor(cA[i], 32);
            pB = __shfl_xor(cB[i], 32);
            const bool hi2 = quad >> 1;
            comb(cA[i], cB[i], hi2 ? pA : cA[i], hi2 ? pB : cB[i],
                               hi2 ? cA[i] : pA, hi2 ? cB[i] : pB);
        }
        float Alo, Blo, Ahi, Bhi;
        comb(Alo, Blo, cA[0], cB[0], cA[1], cB[1]);
        comb(Ahi, Bhi, cA[2], cB[2], cA[3], cB[3]);
        if (quad == 0) {   // transposed [h][c] stores (scattered, overlapped)
            AaggT[(size_t)n * NCHUNK + c_lo]     = Alo;
            BaggT[(size_t)n * NCHUNK + c_lo]     = Blo;
            AaggT[(size_t)n * NCHUNK + c_lo + 1] = Ahi;
            BaggT[(size_t)n * NCHUNK + c_lo + 1] = Bhi;
        }
    }
}

// ---------------------------------------------------------------------------
// Kernel 2: per-channel Hillis-Steele over NCHUNK chunk aggregates.
// grid = 512 channel-blocks x 512 threads. Fully coalesced r/w via [h][c].
// ---------------------------------------------------------------------------
__global__ __launch_bounds__(512) void scan_p2(
    const float* __restrict__ AaggT, const float* __restrict__ BaggT,
    float* __restrict__ HpreT)
{
    const int h = blockIdx.x;
    const int c = threadIdx.x;
    __shared__ float sA[NCHUNK], sB[NCHUNK];

    float A = AaggT[(size_t)h * NCHUNK + c];
    float B = BaggT[(size_t)h * NCHUNK + c];
    sA[c] = A; sB[c] = B;
    __syncthreads();

    for (int off = 1; off < NCHUNK; off <<= 1) {
        float pA = 1.f, pB = 0.f;
        if (c >= off) { pA = sA[c - off]; pB = sB[c - off]; }
        __syncthreads();
        const float nB = A * pB + B;   // uses old A
        const float nA = A * pA;
        A = nA; B = nB;
        sA[c] = A; sB[c] = B;
        __syncthreads();
    }
    const float hp = (c == 0) ? 0.f : sB[c - 1];
    HpreT[(size_t)h * NCHUNK + c] = hp;
}

// ---------------------------------------------------------------------------
// Kernel 3: replay chunk recurrence from HpreT; write bf16 states.
// 1 channel/thread, grid (512 chunks x 2 halves) x 256 threads -> 4 blocks/CU.
// NOTE: writes 'states' which aliases xs_c — safe, gemm_zh is done by now.
// ---------------------------------------------------------------------------
__global__ __launch_bounds__(256) void scan_p3(
    const unsigned int* __restrict__ ab_ws, const float* __restrict__ HpreT,
    unsigned short* __restrict__ states)
{
    const int tid = threadIdx.x;
    const int c   = blockIdx.x;
    const int ch  = blockIdx.y * 256 + tid;
    float H = HpreT[(size_t)ch * NCHUNK + c];       // one-time gather
    const size_t base = (size_t)(c * LCHUNK) * DMODEL + ch;
    #pragma unroll 8
    for (int i = 0; i < LCHUNK; ++i) {
        const unsigned u = ab_ws[base + (size_t)i * DMODEL];
        const float a = bf2f((unsigned short)(u & 0xFFFFu));
        const float b = bf2f((unsigned short)(u >> 16));
        H = a * H + b;
        states[base + (size_t)i * DMODEL] = f2bf(H);
    }
}

// ---------------------------------------------------------------------------
// Kernel 4: out = states @ Wo^T + bo  (fp32 out). grid dim3(128,4), bm fast.
// Same depth-2 counted-vmcnt pipeline; 2 arrays -> vmcnt(4); 48KB LDS ->
// 3 blocks/CU.
// ---------------------------------------------------------------------------
__global__ __launch_bounds__(256, 3) void gemm_out(
    const bf16* __restrict__ states, const bf16* __restrict__ Wo, const float* __restrict__ bo,
    float* __restrict__ out)
{
    __shared__ __bf16 As[3][128 * BK];
    __shared__ __bf16 Bs[3][128 * BK];

    const int tid  = threadIdx.x;
    const int bm   = blockIdx.x;
    const int bn   = blockIdx.y;
    const int lane = tid & 63;
    const int wave = tid >> 6;
    const int wm   = wave >> 1;
    const int wn   = wave & 1;
    const int quad = lane >> 4;
    const int col  = lane & 15;

    f32x4 acc[4][4];
    #pragma unroll
    for (int i = 0; i < 4; ++i)
        #pragma unroll
        for (int j = 0; j < 4; ++j)
            acc[i][j] = (f32x4){0.f, 0.f, 0.f, 0.f};

    const int wrow = tid >> 2;
    const int wq   = (tid & 3) ^ ((tid >> 3) & 3);
    const bf16* ag = states + (size_t)(bm * 128 + wrow) * DMODEL + wq * 8;
    const bf16* bg = Wo     + (size_t)(bn * 128 + wrow) * DMODEL + wq * 8;

    const int fq = quad ^ ((col >> 1) & 3);
    int offA[4], offB[4];
    #pragma unroll
    for (int i = 0; i < 4; ++i) {
        offA[i] = (wm * 64 + i * 16 + col) * BK + fq * 8;
        offB[i] = (wn * 64 + i * 16 + col) * BK + fq * 8;
    }

    auto STAGE = [&](int t, int p) {
        const int k0 = t * BK;
        #pragma unroll
        for (int it = 0; it < 2; ++it) {
            const int chunk = it * 256 + tid;
            load_lds16(ag + (size_t)(it * 64) * DMODEL + k0, &As[p][chunk * 8]);
            load_lds16(bg + (size_t)(it * 64) * DMODEL + k0, &Bs[p][chunk * 8]);
        }
    };
    auto COMPUTE = [&](int p) {
        bf16x8 af[4], bf[4];
        #pragma unroll
        for (int i = 0; i < 4; ++i) {
            af[i] = *(const bf16x8*)&As[p][offA[i]];
            bf[i] = *(const bf16x8*)&Bs[p][offB[i]];
        }
        #pragma unroll
        for (int i = 0; i < 4; ++i)
            #pragma unroll
            for (int j = 0; j < 4; ++j)
                acc[i][j] = __builtin_amdgcn_mfma_f32_16x16x32_bf16(af[i], bf[j], acc[i][j], 0, 0, 0);
    };

    STAGE(0, 0); STAGE(1, 1);
    int pc = 0;
    for (int t = 0; t < NT - 1; ++t) {
        asm volatile("s_waitcnt vmcnt(4)" ::: "memory");
        __builtin_amdgcn_s_barrier();
        __builtin_amdgcn_sched_barrier(0);
        if (t + 2 < NT) {
            const int pn = (pc == 0) ? 2 : pc - 1;
            STAGE(t + 2, pn);
        }
        COMPUTE(pc);
        pc = (pc == 2) ? 0 : pc + 1;
    }
    asm volatile("s_waitcnt vmcnt(0)" ::: "memory");
    __builtin_amdgcn_s_barrier();
    __builtin_amdgcn_sched_barrier(0);
    COMPUTE(pc);

    #pragma unroll
    for (int j = 0; j < 4; ++j) {
        const int n = bn * 128 + wn * 64 + j * 16 + col;
        const float bov = bo[n];
        #pragma unroll
        for (int i = 0; i < 4; ++i) {
            const int mbase = bm * 128 + wm * 64 + i * 16 + quad * 4;
            #pragma unroll
            for (int r = 0; r < 4; ++r)
                out[(size_t)(mbase + r) * DMODEL + n] = acc[i][j][r] + bov;
        }
    }
}

// ---------------------------------------------------------------------------
extern "C" void kernel_launch(void* const* d_in, const int* in_sizes, int n_in,
                              void* d_out, int out_size, void* d_ws, size_t ws_size,
                              hipStream_t stream)
{
    const float* xs = (const float*)d_in[0];
    const float* Wz = (const float*)d_in[1];
    const float* bz = (const float*)d_in[2];
    const float* Wh = (const float*)d_in[3];
    const float* bh = (const float*)d_in[4];
    const float* Wo = (const float*)d_in[5];
    const float* bo = (const float*)d_in[6];
    float* out = (float*)d_out;

    char* w = (char*)d_ws;
    bf16*  Wz_c   = (bf16*) (w);                     //    524,288
    bf16*  Wh_c   = (bf16*) (w + 524288ull);         //    524,288
    bf16*  Wo_c   = (bf16*) (w + 1048576ull);        //    524,288
    unsigned int*   ab_ws  = (unsigned int*)  (w + 1572864ull);  // 33,554,432
    unsigned short* states = (unsigned short*)(w + 35127296ull); // 16,777,216
    float* AaggT  = (float*)(w + 51904512ull);       //  1,048,576
    float* BaggT  = (float*)(w + 52953088ull);       //  1,048,576
    float* HpreT  = (float*)(w + 54001664ull);       //  1,048,576
    // xs_c aliases states: xs_c dead after gemm_zh; states born in scan_p3.
    bf16*  xs_c   = (bf16*) states;

    k_convert<<<(N4_ALL + 255) / 256, 256, 0, stream>>>(xs, Wz, Wh, Wo, xs_c, Wz_c, Wh_c, Wo_c);
    gemm_zh<<<dim3(128, 4), 256, 0, stream>>>(xs_c, Wz_c, bz, Wh_c, bh, ab_ws, AaggT, BaggT);
    scan_p2<<<DMODEL, NCHUNK, 0, stream>>>(AaggT, BaggT, HpreT);
    scan_p3<<<dim3(NCHUNK, 2), 256, 0, stream>>>(ab_ws, HpreT, states);
    gemm_out<<<dim3(128, 4), 256, 0, stream>>>((const bf16*)states, Wo_c, bo, out);
}

// Round 3
// 150.157 us; speedup vs baseline: 1.1146x; 1.0108x over previous
//
#include <hip/hip_runtime.h>
#include <hip/hip_bf16.h>
#include <cstdint>
#include <cmath>

// Problem constants — inputs/outputs are fp32.
// LESSON (R5): cooperative grid.sync() ~50us on MI355X — use kernel boundaries.
// LESSON (R6): scan topology cheap; GEMM staging + scatter are the fat.
// LESSON (R7): [128][64] LDS = 16-way conflict; XOR slot swizzle -> 0 (verified).
// LESSON (R8): __syncthreads() drains vmcnt(0)/K-step; BK=32 2-buf regressed
// (gemm_zh 57us, all pipes <16% = latency-bound).
// LESSON (R9 = R2 input): depth-2 counted-vmcnt 1-phase loop recovered to
// baseline 152us — 2-phase-regime ceiling (m233: stage+bar = 72% of path).
// R3: port both GEMMs to the m201 8-phase-style template: 256x128 tile,
// 512 thr / 8 waves, BK=64 as 2x32 halves, 2 tile-buffers, counted vmcnt(4)
// per half (never 0 in loop), barrier only at fresh-half consumption,
// setprio around MFMA clusters. Accumulation k-order unchanged (bit-identical
// numerics; absmax must stay 0.0048828).
#define T_SEQ 16384
#define DMODEL 512
#define NCHUNK 512        // scan chunks (= T_SEQ/LCHUNK)
#define LCHUNK 32
#define W_N    (DMODEL * DMODEL)
#define N4_W   (W_N / 4)
#define N4_W3  (3 * N4_W)
#define N4_X   (T_SEQ * DMODEL / 4)
#define N4_ALL (N4_W3 + N4_X)
#define NTILE  8           // K tiles of 64 (= DMODEL/64)

typedef __bf16 bf16x8 __attribute__((ext_vector_type(8)));
typedef float  f32x4  __attribute__((ext_vector_type(4)));

using bf16 = __hip_bfloat16;

__device__ __forceinline__ void load_lds16(const void* g, void* l) {
    __builtin_amdgcn_global_load_lds((const __attribute__((address_space(1))) void*)g,
                                     (__attribute__((address_space(3))) void*)l,
                                     16, 0, 0);
}

__device__ __forceinline__ unsigned short f2bf(float f) {
    union { float f; unsigned u; } v; v.f = f;
    const unsigned r = (v.u + 0x7FFFu + ((v.u >> 16) & 1u)) >> 16;
    return (unsigned short)r;
}
__device__ __forceinline__ float bf2f(unsigned short u) {
    union { unsigned u; float f; } v; v.u = ((unsigned)u) << 16;
    return v.f;
}

// ordered pair-combine: first=(fA,fB) then second=(sA,sB)
__device__ __forceinline__ void comb(float& A, float& B, float fA, float fB,
                                     float sA, float sB) {
    A = fA * sA;
    B = sA * fB + sB;
}

// ---------------------------------------------------------------------------
// Kernel 0: convert Wz, Wh, Wo AND xs fp32 -> bf16 (~52 MB, ~9 us).
// Buys the GEMMs a homogeneous global_load_lds path (counted-vmcnt safe).
// ---------------------------------------------------------------------------
__global__ __launch_bounds__(256) void k_convert(
    const float* __restrict__ xs,
    const float* __restrict__ Wz, const float* __restrict__ Wh,
    const float* __restrict__ Wo,
    bf16* __restrict__ xs_c, bf16* __restrict__ Wz_c,
    bf16* __restrict__ Wh_c, bf16* __restrict__ Wo_c)
{
    const int i = blockIdx.x * 256 + threadIdx.x;
    if (i >= N4_ALL) return;
    const float* src; bf16* dst; int o;
    if (i < N4_W3) {
        const int w = i >> 16; o = i & 65535;
        src = (w == 0) ? Wz : (w == 1) ? Wh : Wo;
        dst = (w == 0) ? Wz_c : (w == 1) ? Wh_c : Wo_c;
    } else {
        o = i - N4_W3; src = xs; dst = xs_c;
    }
    const float4 v = ((const float4*)src)[o];
    ushort4 r;
    r.x = f2bf(v.x); r.y = f2bf(v.y); r.z = f2bf(v.z); r.w = f2bf(v.w);
    ((ushort4*)dst)[o] = r;
}

// ---------------------------------------------------------------------------
// Kernel 1: fused dual GEMM + scan phase 1 — m201-style template.
// Tile 256x128, 512 threads (8 waves: wm 0..3 x wn 0..1, wave tile 64x64 per
// GEMM). BK=64 staged as two 32-halves; 2 tile-buffers (128 KB LDS, 1 blk/CU).
// Per tile: 4 phases {Z(k0), H(k0), Z(k1), H(k1)}; counted vmcnt(4) + barrier
// only before fresh-half phases (A,C); stage half of tile t+1 there. Prefetch
// window = 4 phases (~full tile of compute). Swizzle: physical 16B slot q of a
// 32-elem row r holds logical q ^ ((r>>1)&3) (verified conflict-free).
// ---------------------------------------------------------------------------
__global__ __launch_bounds__(512, 2) void gemm_zh(
    const bf16* __restrict__ xs_c, const bf16* __restrict__ Wz, const float* __restrict__ bz,
    const bf16* __restrict__ Wh, const float* __restrict__ bh,
    unsigned int* __restrict__ ab_ws,
    float* __restrict__ AaggT, float* __restrict__ BaggT)
{
    __shared__ __bf16 As[2][2][256 * 32];   // 64 KB
    __shared__ __bf16 Zs[2][2][128 * 32];   // 32 KB
    __shared__ __bf16 Hs[2][2][128 * 32];   // 32 KB

    const int tid  = threadIdx.x;
    const int bm   = blockIdx.x;   // 0..63  (M tile of 256)
    const int bn   = blockIdx.y;   // 0..3   (N tile of 128)
    const int lane = tid & 63;
    const int wave = tid >> 6;     // 0..7
    const int wm   = wave >> 1;    // 0..3
    const int wn   = wave & 1;     // 0..1
    const int quad = lane >> 4;
    const int col  = lane & 15;

    f32x4 accz[4][4], acch[4][4];
    #pragma unroll
    for (int i = 0; i < 4; ++i)
        #pragma unroll
        for (int j = 0; j < 4; ++j) {
            accz[i][j] = (f32x4){0.f, 0.f, 0.f, 0.f};
            acch[i][j] = (f32x4){0.f, 0.f, 0.f, 0.f};
        }

    // staging: linear LDS dest, pre-swizzled global source.
    const int srow = tid >> 2;                        // 0..127
    const int wq   = (tid & 3) ^ ((tid >> 3) & 3);
    const bf16* ag = xs_c + (size_t)(bm * 256 + srow) * DMODEL + wq * 8;
    const bf16* zg = Wz   + (size_t)(bn * 128 + srow) * DMODEL + wq * 8;
    const bf16* hg = Wh   + (size_t)(bn * 128 + srow) * DMODEL + wq * 8;

    // fragment read offsets (swizzled slot fq within 32-elem rows)
    const int fq = quad ^ ((col >> 1) & 3);
    int offA[4], offB[4];
    #pragma unroll
    for (int i = 0; i < 4; ++i) {
        offA[i] = (wm * 64 + i * 16 + col) * 32 + fq * 8;
        offB[i] = (wn * 64 + i * 16 + col) * 32 + fq * 8;
    }

    // 4 loads per half-tile per thread (A x2, Z, H)
    auto STAGE_HALF = [&](int t, int h) {
        const int b  = t & 1;
        const int ko = t * 64 + h * 32;
        load_lds16(ag + ko,                          &As[b][h][tid * 8]);
        load_lds16(ag + (size_t)128 * DMODEL + ko,   &As[b][h][(512 + tid) * 8]);
        load_lds16(zg + ko,                          &Zs[b][h][tid * 8]);
        load_lds16(hg + ko,                          &Hs[b][h][tid * 8]);
    };

    // prologue: tile 0 fully in flight (8 loads/thread)
    STAGE_HALF(0, 0); STAGE_HALF(0, 1);

    #pragma unroll
    for (int t = 0; t < NTILE; ++t) {
        const int b = t & 1;
        bf16x8 af[4], zf[4], hf[4];

        // ---- Phase A: Z-gemm, half 0 (fresh) ----
        asm volatile("s_waitcnt vmcnt(4)" ::: "memory");   // my H0(t) landed
        __builtin_amdgcn_s_barrier();                      // everyone's landed
        __builtin_amdgcn_sched_barrier(0);
        if (t + 1 < NTILE) STAGE_HALF(t + 1, 0);
        #pragma unroll
        for (int i = 0; i < 4; ++i) {
            af[i] = *(const bf16x8*)&As[b][0][offA[i]];
            zf[i] = *(const bf16x8*)&Zs[b][0][offB[i]];
        }
        __builtin_amdgcn_s_setprio(1);
        #pragma unroll
        for (int i = 0; i < 4; ++i)
            #pragma unroll
            for (int j = 0; j < 4; ++j)
                accz[i][j] = __builtin_amdgcn_mfma_f32_16x16x32_bf16(af[i], zf[j], accz[i][j], 0, 0, 0);
        __builtin_amdgcn_s_setprio(0);

        // ---- Phase B: H-gemm, half 0 (af reused in regs) ----
        #pragma unroll
        for (int j = 0; j < 4; ++j)
            hf[j] = *(const bf16x8*)&Hs[b][0][offB[j]];
        __builtin_amdgcn_s_setprio(1);
        #pragma unroll
        for (int i = 0; i < 4; ++i)
            #pragma unroll
            for (int j = 0; j < 4; ++j)
                acch[i][j] = __builtin_amdgcn_mfma_f32_16x16x32_bf16(af[i], hf[j], acch[i][j], 0, 0, 0);
        __builtin_amdgcn_s_setprio(0);

        // ---- Phase C: Z-gemm, half 1 (fresh) ----
        if (t + 1 < NTILE) {
            asm volatile("s_waitcnt vmcnt(4)" ::: "memory");
        } else {
            asm volatile("s_waitcnt vmcnt(0)" ::: "memory");
        }
        __builtin_amdgcn_s_barrier();
        __builtin_amdgcn_sched_barrier(0);
        if (t + 1 < NTILE) STAGE_HALF(t + 1, 1);
        #pragma unroll
        for (int i = 0; i < 4; ++i) {
            af[i] = *(const bf16x8*)&As[b][1][offA[i]];
            zf[i] = *(const bf16x8*)&Zs[b][1][offB[i]];
        }
        __builtin_amdgcn_s_setprio(1);
        #pragma unroll
        for (int i = 0; i < 4; ++i)
            #pragma unroll
            for (int j = 0; j < 4; ++j)
                accz[i][j] = __builtin_amdgcn_mfma_f32_16x16x32_bf16(af[i], zf[j], accz[i][j], 0, 0, 0);
        __builtin_amdgcn_s_setprio(0);

        // ---- Phase D: H-gemm, half 1 ----
        #pragma unroll
        for (int j = 0; j < 4; ++j)
            hf[j] = *(const bf16x8*)&Hs[b][1][offB[j]];
        __builtin_amdgcn_s_setprio(1);
        #pragma unroll
        for (int i = 0; i < 4; ++i)
            #pragma unroll
            for (int j = 0; j < 4; ++j)
                acch[i][j] = __builtin_amdgcn_mfma_f32_16x16x32_bf16(af[i], hf[j], acch[i][j], 0, 0, 0);
        __builtin_amdgcn_s_setprio(0);
    }

    // epilogue: D layout col=lane&15 (n), row=quad*4+reg (m)
    const int c_lo = bm * 8 + wm * 2;      // 8 chunks per 256-row tile
    #pragma unroll
    for (int j = 0; j < 4; ++j) {
        const int n = bn * 128 + wn * 64 + j * 16 + col;
        const float bzv = bz[n];
        const float bhv = bh[n];
        float cA[4], cB[4];
        #pragma unroll
        for (int i = 0; i < 4; ++i) {
            const int mbase = bm * 256 + wm * 64 + i * 16 + quad * 4;
            float A = 1.f, B = 0.f;
            #pragma unroll
            for (int r = 0; r < 4; ++r) {
                const float zpre = accz[i][j][r] + bzv;
                const float hpre = acch[i][j][r] + bhv;
                const float z = 1.f / (1.f + __expf(-zpre));
                const float a = 1.f - z;
                const float b = z * hpre;
                const size_t idx = (size_t)(mbase + r) * DMODEL + n;
                ab_ws[idx] = (unsigned)f2bf(a) | ((unsigned)f2bf(b) << 16);
                A = a * A;
                B = a * B + b;
            }
            cA[i] = A; cB[i] = B;
        }
        #pragma unroll
        for (int i = 0; i < 4; ++i) {
            float pA = __shfl_xor(cA[i], 16);
            float pB = __shfl_xor(cB[i], 16);
            const bool hi1 = quad & 1;
            comb(cA[i], cB[i], hi1 ? pA : cA[i], hi1 ? pB : cB[i],
                               hi1 ? cA[i] : pA, hi1 ? cB[i] : pB);
            pA = __shfl_xor(cA[i], 32);
            pB = __shfl_xor(cB[i], 32);
            const bool hi2 = quad >> 1;
            comb(cA[i], cB[i], hi2 ? pA : cA[i], hi2 ? pB : cB[i],
                               hi2 ? cA[i] : pA, hi2 ? cB[i] : pB);
        }
        float Alo, Blo, Ahi, Bhi;
        comb(Alo, Blo, cA[0], cB[0], cA[1], cB[1]);
        comb(Ahi, Bhi, cA[2], cB[2], cA[3], cB[3]);
        if (quad == 0) {   // transposed [h][c] stores (scattered, overlapped)
            AaggT[(size_t)n * NCHUNK + c_lo]     = Alo;
            BaggT[(size_t)n * NCHUNK + c_lo]     = Blo;
            AaggT[(size_t)n * NCHUNK + c_lo + 1] = Ahi;
            BaggT[(size_t)n * NCHUNK + c_lo + 1] = Bhi;
        }
    }
}

// ---------------------------------------------------------------------------
// Kernel 2: per-channel Hillis-Steele over NCHUNK chunk aggregates.
// ---------------------------------------------------------------------------
__global__ __launch_bounds__(512) void scan_p2(
    const float* __restrict__ AaggT, const float* __restrict__ BaggT,
    float* __restrict__ HpreT)
{
    const int h = blockIdx.x;
    const int c = threadIdx.x;
    __shared__ float sA[NCHUNK], sB[NCHUNK];

    float A = AaggT[(size_t)h * NCHUNK + c];
    float B = BaggT[(size_t)h * NCHUNK + c];
    sA[c] = A; sB[c] = B;
    __syncthreads();

    for (int off = 1; off < NCHUNK; off <<= 1) {
        float pA = 1.f, pB = 0.f;
        if (c >= off) { pA = sA[c - off]; pB = sB[c - off]; }
        __syncthreads();
        const float nB = A * pB + B;   // uses old A
        const float nA = A * pA;
        A = nA; B = nB;
        sA[c] = A; sB[c] = B;
        __syncthreads();
    }
    const float hp = (c == 0) ? 0.f : sB[c - 1];
    HpreT[(size_t)h * NCHUNK + c] = hp;
}

// ---------------------------------------------------------------------------
// Kernel 3: replay chunk recurrence from HpreT; write bf16 states.
// 1 channel/thread, grid (512 chunks x 2 halves) x 256 threads -> 4 blk/CU.
// NOTE: writes 'states' which aliases xs_c — safe, gemm_zh done by now.
// ---------------------------------------------------------------------------
__global__ __launch_bounds__(256) void scan_p3(
    const unsigned int* __restrict__ ab_ws, const float* __restrict__ HpreT,
    unsigned short* __restrict__ states)
{
    const int tid = threadIdx.x;
    const int c   = blockIdx.x;
    const int ch  = blockIdx.y * 256 + tid;
    float H = HpreT[(size_t)ch * NCHUNK + c];       // one-time gather
    const size_t base = (size_t)(c * LCHUNK) * DMODEL + ch;
    #pragma unroll 8
    for (int i = 0; i < LCHUNK; ++i) {
        const unsigned u = ab_ws[base + (size_t)i * DMODEL];
        const float a = bf2f((unsigned short)(u & 0xFFFFu));
        const float b = bf2f((unsigned short)(u >> 16));
        H = a * H + b;
        states[base + (size_t)i * DMODEL] = f2bf(H);
    }
}

// ---------------------------------------------------------------------------
// Kernel 4: out = states @ Wo^T + bo. Same m201-style template, single GEMM:
// tile 256x128, 512 thr / 8 waves, BK=64 as 2x32 halves, 96 KB LDS,
// 2 phases/tile with counted vmcnt(3), stage 3 loads/half.
// ---------------------------------------------------------------------------
__global__ __launch_bounds__(512, 2) void gemm_out(
    const bf16* __restrict__ states, const bf16* __restrict__ Wo, const float* __restrict__ bo,
    float* __restrict__ out)
{
    __shared__ __bf16 As[2][2][256 * 32];   // 64 KB
    __shared__ __bf16 Bs[2][2][128 * 32];   // 32 KB

    const int tid  = threadIdx.x;
    const int bm   = blockIdx.x;   // 0..63
    const int bn   = blockIdx.y;   // 0..3
    const int lane = tid & 63;
    const int wave = tid >> 6;
    const int wm   = wave >> 1;    // 0..3
    const int wn   = wave & 1;     // 0..1
    const int quad = lane >> 4;
    const int col  = lane & 15;

    f32x4 acc[4][4];
    #pragma unroll
    for (int i = 0; i < 4; ++i)
        #pragma unroll
        for (int j = 0; j < 4; ++j)
            acc[i][j] = (f32x4){0.f, 0.f, 0.f, 0.f};

    const int srow = tid >> 2;
    const int wq   = (tid & 3) ^ ((tid >> 3) & 3);
    const bf16* ag = states + (size_t)(bm * 256 + srow) * DMODEL + wq * 8;
    const bf16* bg = Wo     + (size_t)(bn * 128 + srow) * DMODEL + wq * 8;

    const int fq = quad ^ ((col >> 1) & 3);
    int offA[4], offB[4];
    #pragma unroll
    for (int i = 0; i < 4; ++i) {
        offA[i] = (wm * 64 + i * 16 + col) * 32 + fq * 8;
        offB[i] = (wn * 64 + i * 16 + col) * 32 + fq * 8;
    }

    auto STAGE_HALF = [&](int t, int h) {
        const int b  = t & 1;
        const int ko = t * 64 + h * 32;
        load_lds16(ag + ko,                        &As[b][h][tid * 8]);
        load_lds16(ag + (size_t)128 * DMODEL + ko, &As[b][h][(512 + tid) * 8]);
        load_lds16(bg + ko,                        &Bs[b][h][tid * 8]);
    };

    STAGE_HALF(0, 0); STAGE_HALF(0, 1);

    #pragma unroll
    for (int t = 0; t < NTILE; ++t) {
        const int b = t & 1;
        bf16x8 af[4], bf[4];

        // ---- Phase 0: k-half 0 (fresh) ----
        asm volatile("s_waitcnt vmcnt(3)" ::: "memory");
        __builtin_amdgcn_s_barrier();
        __builtin_amdgcn_sched_barrier(0);
        if (t + 1 < NTILE) STAGE_HALF(t + 1, 0);
        #pragma unroll
        for (int i = 0; i < 4; ++i) {
            af[i] = *(const bf16x8*)&As[b][0][offA[i]];
            bf[i] = *(const bf16x8*)&Bs[b][0][offB[i]];
        }
        __builtin_amdgcn_s_setprio(1);
        #pragma unroll
        for (int i = 0; i < 4; ++i)
            #pragma unroll
            for (int j = 0; j < 4; ++j)
                acc[i][j] = __builtin_amdgcn_mfma_f32_16x16x32_bf16(af[i], bf[j], acc[i][j], 0, 0, 0);
        __builtin_amdgcn_s_setprio(0);

        // ---- Phase 1: k-half 1 (fresh) ----
        if (t + 1 < NTILE) {
            asm volatile("s_waitcnt vmcnt(3)" ::: "memory");
        } else {
            asm volatile("s_waitcnt vmcnt(0)" ::: "memory");
        }
        __builtin_amdgcn_s_barrier();
        __builtin_amdgcn_sched_barrier(0);
        if (t + 1 < NTILE) STAGE_HALF(t + 1, 1);
        #pragma unroll
        for (int i = 0; i < 4; ++i) {
            af[i] = *(const bf16x8*)&As[b][1][offA[i]];
            bf[i] = *(const bf16x8*)&Bs[b][1][offB[i]];
        }
        __builtin_amdgcn_s_setprio(1);
        #pragma unroll
        for (int i = 0; i < 4; ++i)
            #pragma unroll
            for (int j = 0; j < 4; ++j)
                acc[i][j] = __builtin_amdgcn_mfma_f32_16x16x32_bf16(af[i], bf[j], acc[i][j], 0, 0, 0);
        __builtin_amdgcn_s_setprio(0);
    }

    #pragma unroll
    for (int j = 0; j < 4; ++j) {
        const int n = bn * 128 + wn * 64 + j * 16 + col;
        const float bov = bo[n];
        #pragma unroll
        for (int i = 0; i < 4; ++i) {
            const int mbase = bm * 256 + wm * 64 + i * 16 + quad * 4;
            #pragma unroll
            for (int r = 0; r < 4; ++r)
                out[(size_t)(mbase + r) * DMODEL + n] = acc[i][j][r] + bov;
        }
    }
}

// ---------------------------------------------------------------------------
extern "C" void kernel_launch(void* const* d_in, const int* in_sizes, int n_in,
                              void* d_out, int out_size, void* d_ws, size_t ws_size,
                              hipStream_t stream)
{
    const float* xs = (const float*)d_in[0];
    const float* Wz = (const float*)d_in[1];
    const float* bz = (const float*)d_in[2];
    const float* Wh = (const float*)d_in[3];
    const float* bh = (const float*)d_in[4];
    const float* Wo = (const float*)d_in[5];
    const float* bo = (const float*)d_in[6];
    float* out = (float*)d_out;

    char* w = (char*)d_ws;
    bf16*  Wz_c   = (bf16*) (w);                     //    524,288
    bf16*  Wh_c   = (bf16*) (w + 524288ull);         //    524,288
    bf16*  Wo_c   = (bf16*) (w + 1048576ull);        //    524,288
    unsigned int*   ab_ws  = (unsigned int*)  (w + 1572864ull);  // 33,554,432
    unsigned short* states = (unsigned short*)(w + 35127296ull); // 16,777,216
    float* AaggT  = (float*)(w + 51904512ull);       //  1,048,576
    float* BaggT  = (float*)(w + 52953088ull);       //  1,048,576
    float* HpreT  = (float*)(w + 54001664ull);       //  1,048,576
    // xs_c aliases states: xs_c dead after gemm_zh; states born in scan_p3.
    bf16*  xs_c   = (bf16*) states;

    k_convert<<<(N4_ALL + 255) / 256, 256, 0, stream>>>(xs, Wz, Wh, Wo, xs_c, Wz_c, Wh_c, Wo_c);
    gemm_zh<<<dim3(64, 4), 512, 0, stream>>>(xs_c, Wz_c, bz, Wh_c, bh, ab_ws, AaggT, BaggT);
    scan_p2<<<DMODEL, NCHUNK, 0, stream>>>(AaggT, BaggT, HpreT);
    scan_p3<<<dim3(NCHUNK, 2), 256, 0, stream>>>(ab_ws, HpreT, states);
    gemm_out<<<dim3(64, 4), 512, 0, stream>>>((const bf16*)states, Wo_c, bo, out);
}